// Round 24
// baseline (667.448 us; speedup 1.0000x reference)
//
#include <hip/hip_runtime.h>
#include <hip/hip_bf16.h>
#include <cmath>

typedef __bf16 bf16_t;
typedef bf16_t bf16x8 __attribute__((ext_vector_type(8)));
typedef float f32x4 __attribute__((ext_vector_type(4)));

__device__ __forceinline__ f32x4 zero4(){ f32x4 z; z[0]=0.f; z[1]=0.f; z[2]=0.f; z[3]=0.f; return z; }

__device__ __forceinline__ bf16x8 cvt8(float4 a, float4 b){
  bf16x8 r;
  r[0]=(bf16_t)a.x; r[1]=(bf16_t)a.y; r[2]=(bf16_t)a.z; r[3]=(bf16_t)a.w;
  r[4]=(bf16_t)b.x; r[5]=(bf16_t)b.y; r[6]=(bf16_t)b.z; r[7]=(bf16_t)b.w;
  return r;
}

__device__ __forceinline__ float gelu_tanh_f(float x){
  float x3 = x*x*x;
  return 0.5f*x*(1.0f + tanhf(0.7978845608028654f*(x + 0.044715f*x3)));
}

// chunk swizzle for bf16 A-operands: 16B chunk (col>>3)&3 XOR'd by (row>>1)&3
__device__ __forceinline__ int swz_col(int row, int col){
  return (col & ~31) | (((((col>>3)&3) ^ ((row>>1)&3)))<<3) | (col&7);
}

#if defined(__has_builtin)
#if __has_builtin(__builtin_amdgcn_global_load_lds)
#define HAS_GLDS 1
#endif
#endif

__device__ __forceinline__ void glds16(const void* g, void* l){
#ifdef HAS_GLDS
  __builtin_amdgcn_global_load_lds(
      (const __attribute__((address_space(1))) unsigned int*)g,
      (__attribute__((address_space(3))) unsigned int*)l, 16, 0, 0);
#else
  *(float4*)((char*)l + (threadIdx.x & 63)*16) = *(const float4*)g;
#endif
}

// ============ GEMM body: C[128,128] block, BK=32, 4 waves (2x2), 256 thr ============
// r19 raw-barrier schedule at 3 blocks/CU (the untested A/B axis):
// s_barrier + lgkmcnt(0) only (no vmcnt(0) drain); A glds 3-ring issued 2 tiles
// ahead; B fp32 reg slot loaded 2 steps ahead, its ds_write reg-wait retires
// older VMEM in-order.  LDS 44 KB x 3 blocks = 132 KB; launch_bounds(256,3).
// EPI bits: 1 = fp32 store to Cf, 2 = bf16 linear to Cb, 4 = bf16 swz32 to Cb, 8 = gelu
template<int EPI>
__device__ __forceinline__ void gemm_body(
    const bf16_t* __restrict__ A, const float* __restrict__ Wt,
    const float* __restrict__ biast,
    float* __restrict__ Cf, bf16_t* __restrict__ Cb,
    int Nc, int K, int kt0, int ktn, int brow, int ccol0)
{
  __shared__ __align__(16) bf16_t As[3][128*32];   // 3 x 8 KB ring
  __shared__ __align__(16) bf16_t Bs[2][128*40];   // 2 x 10 KB (rows padded 80B)

  const int tid  = threadIdx.x;          // 0..255
  const int lane = tid & 63;
  const int wave = tid >> 6;             // 0..3
  const int wr = wave >> 1, wc = wave & 1;
  const int ca = ((lane>>4) ^ ((lane>>1)&3))*8;

  const bf16_t* srcA = A + (size_t)(brow + (tid>>2))*K + (tid&3)*8;
  const float*  srcB = Wt + (size_t)(tid>>1)*K + (tid&1)*16;

  auto issueA = [&](int buf, int kt){
    bf16_t* dA = &As[buf][wave*512];
    glds16(srcA + (size_t)kt*32,                 dA);
    glds16(srcA + (size_t)64*K + (size_t)kt*32,  dA + 2048);
  };
  auto loadB = [&](int kt, float4* g){
    const float4* p = (const float4*)(srcB + (size_t)kt*32);
    g[0]=p[0]; g[1]=p[1]; g[2]=p[2]; g[3]=p[3];
  };
  auto writeB = [&](int buf, const float4* g){
    bf16_t* d = &Bs[buf][(tid>>1)*40 + (tid&1)*16];
    *(bf16x8*)d     = cvt8(g[0], g[1]);
    *(bf16x8*)(d+8) = cvt8(g[2], g[3]);
  };

  f32x4 acc[4][4];
  #pragma unroll
  for (int m=0;m<4;m++)
    #pragma unroll
    for (int n=0;n<4;n++) acc[m][n] = zero4();

  auto ck = [&](int x){ return kt0 + (x < ktn ? x : ktn-1); };

  float4 sB[4];
  // ---- prologue: A(0),A(1) issued; B(0) staged; sB = B(1) left in flight
  issueA(0, ck(0));
  issueA(1, ck(1));
  {
    float4 g[4];
    loadB(ck(0), g);
    writeB(0, g);            // reg-wait on g retires A(0),A(1),B(0) (in-order)
  }
  loadB(ck(1), sB);
  asm volatile("s_waitcnt lgkmcnt(0)" ::: "memory");
  __builtin_amdgcn_s_barrier();

  for (int t=0; t<ktn; ++t){
    const int ra = t % 3, rb = t & 1;
    issueA((t+2)%3, ck(t+2));
    float4 gn[4];
    loadB(ck(t+2), gn);

    bf16x8 af[4], bfr[4];
    #pragma unroll
    for (int m=0;m<4;m++)
      af[m] = *(const bf16x8*)&As[ra][(wr*64 + m*16 + (lane&15))*32 + ca];
    #pragma unroll
    for (int n=0;n<4;n++)
      bfr[n] = *(const bf16x8*)&Bs[rb][(wc*64 + n*16 + (lane&15))*40 + (lane>>4)*8];
    #pragma unroll
    for (int m=0;m<4;m++)
      #pragma unroll
      for (int n=0;n<4;n++)
        acc[m][n] = __builtin_amdgcn_mfma_f32_16x16x32_bf16(af[m], bfr[n], acc[m][n], 0,0,0);

    writeB((t+1)&1, sB);     // sB = B(t+1), issued last step; wait retires A(t+1) too
    #pragma unroll
    for (int j=0;j<4;j++) sB[j] = gn[j];
    asm volatile("s_waitcnt lgkmcnt(0)" ::: "memory");
    __builtin_amdgcn_s_barrier();
  }

  #pragma unroll
  for (int m=0;m<4;m++){
    #pragma unroll
    for (int n=0;n<4;n++){
      const int col = wc*64 + n*16 + (lane&15);
      const float bv = biast ? biast[col] : 0.f;
      #pragma unroll
      for (int r=0;r<4;r++){
        const int gm = brow + wr*64 + m*16 + (lane>>4)*4 + r;
        float v = acc[m][n][r] + bv;
        if (EPI & 8) v = gelu_tanh_f(v);
        if (EPI & 1) Cf[(size_t)gm*Nc + ccol0 + col] = v;
        if (EPI & 2) Cb[(size_t)gm*Nc + ccol0 + col] = (bf16_t)v;
        if (EPI & 4) Cb[(size_t)gm*Nc + swz_col(gm, ccol0 + col)] = (bf16_t)v;
      }
    }
  }
}

// XCD-grouped decode: lin = r + 8*(m + 4*q); o = r + 8q. The 4 m-blocks sharing a
// W-tile are congruent mod 8 -> same XCD L2. o-count must be % 8 == 0.
// Cb/Cf are pre-offset by the split-K plane (z*512*N) for partial outputs.
template<int EPI>
__global__ __launch_bounds__(256,3) void gemm_kernel(
    const bf16_t* __restrict__ A, const float* __restrict__ W,
    const float* __restrict__ bias,
    float* __restrict__ Cf, bf16_t* __restrict__ Cb, int N, int K, int nt, int nz)
{
  const int lin = blockIdx.x;
  const int r = lin & 7;
  const int t = lin >> 3;
  const int m = t & 3;
  const int o = r + 8*(t>>2);
  const int n_tile = o % nt;
  const int z = o / nt;
  const int ktn = (K>>5) / nz;
  const float* b = (z==0 && bias) ? bias + n_tile*128 : nullptr;
  gemm_body<EPI>(A, W + (size_t)(n_tile*128)*K, b,
                 (EPI&1) ? Cf + (size_t)z*512*N : nullptr,
                 (EPI&6) ? Cb + (size_t)z*512*N : nullptr,
                 N, K, z*ktn, ktn, m*128, n_tile*128);
}

// fused QKV, split-K=2: o in [0,192): n_tile = o%96 (12288-wide plane), z = o/96
// K=4096 -> 128 K-tiles; each z covers 64 (z*64, ktn=64).  Grid 768 = one
// co-resident round at 3 blocks/CU; bf16 partials (2 planes).
__global__ __launch_bounds__(256,3) void gemm_qkv_kernel(
    const bf16_t* __restrict__ A,
    const float* __restrict__ W0, const float* __restrict__ W1, const float* __restrict__ W2,
    const float* __restrict__ b0, const float* __restrict__ b1, const float* __restrict__ b2,
    bf16_t* __restrict__ Cb)
{
  const int lin = blockIdx.x;
  const int r = lin & 7;
  const int t = lin >> 3;
  const int m = t & 3;
  const int o = r + 8*(t>>2);      // [0,192)
  const int n_tile = o % 96;
  const int z = o / 96;            // 0..1
  const int which = n_tile >> 5;
  const int lc = (n_tile & 31) * 128;
  const float* W    = (which==0) ? W0 : ((which==1) ? W1 : W2);
  const float* bia  = (which==0) ? b0 : ((which==1) ? b1 : b2);
  const float* b = (z==0) ? bia + lc : nullptr;
  gemm_body<2>(A, W + (size_t)lc*4096, b, nullptr,
               Cb + (size_t)z*512*12288,
               12288, 4096, z*64, 64, m*128, n_tile*128);
}

// ============ reduce: qkv partials (2 bf16 planes of [512,12288]) -> q,k,v bf16 linear ============
__global__ __launch_bounds__(256) void reduce_qkv_kernel(
    const bf16_t* __restrict__ p, bf16_t* __restrict__ q,
    bf16_t* __restrict__ k, bf16_t* __restrict__ v)
{
  const size_t plane = (size_t)512*12288;
  const int i = (blockIdx.x*256 + threadIdx.x)*8;   // grid 3072 covers exactly
  bf16x8 w0 = *(const bf16x8*)(p + i);
  bf16x8 w1 = *(const bf16x8*)(p + plane + i);
  bf16x8 val;
  #pragma unroll
  for (int e=0;e<8;e++) val[e] = (bf16_t)((float)w0[e] + (float)w1[e]);
  const int row = i / 12288;
  const int col = i - row*12288;
  bf16_t* dst = (col<4096) ? q : ((col<8192) ? k : v);
  *(bf16x8*)(dst + (size_t)row*4096 + (col & 4095)) = val;
}

// ============ reduce: ffn1 partials (2 bf16 planes of [512,16384]) + gelu -> bf16 swz32 ============
__global__ __launch_bounds__(256) void reduce_gelu_kernel(
    const bf16_t* __restrict__ p, bf16_t* __restrict__ out)
{
  const size_t plane = (size_t)512*16384;
  const int i = (blockIdx.x*256 + threadIdx.x)*8;   // grid 4096 covers exactly
  bf16x8 w0 = *(const bf16x8*)(p + i);
  bf16x8 w1 = *(const bf16x8*)(p + plane + i);
  bf16x8 val;
  #pragma unroll
  for (int e=0;e<8;e++) val[e] = (bf16_t)gelu_tanh_f((float)w0[e] + (float)w1[e]);
  const int row = i >> 14;
  const int col = i & 16383;
  *(bf16x8*)(out + (size_t)row*16384 + (size_t)swz_col(row, col)) = val;
}

// ============ flash attention: grid (8 qblocks, 64 heads), 256 thr, 16 q-rows/wave ============
__global__ void attn_kernel(
    const bf16_t* __restrict__ q, const bf16_t* __restrict__ k,
    const bf16_t* __restrict__ v, bf16_t* __restrict__ ctx)
{
  constexpr int HID = 4096;
  const int qblk = blockIdx.x, head = blockIdx.y;
  const int tid = threadIdx.x, lane = tid & 63, wave = tid >> 6;

  __shared__ __align__(16) bf16_t Ks[128][72];
  __shared__ __align__(16) bf16_t Vt[64][136];
  __shared__ __align__(16) bf16_t Ps[4][16][136];

  bf16x8 qf[2];
  const int qrow0 = qblk*64 + wave*16;
  #pragma unroll
  for (int ks=0;ks<2;ks++)
    qf[ks] = *(const bf16x8*)(q + (size_t)(qrow0 + (lane&15))*HID + head*64 + ks*32 + (lane>>4)*8);

  f32x4 o[4];
  float mrow[4], lrow[4];
  #pragma unroll
  for (int n=0;n<4;n++) o[n] = zero4();
  #pragma unroll
  for (int r=0;r<4;r++){ mrow[r] = -1e30f; lrow[r] = 0.f; }

  for (int t=0; t<4; ++t){
    __syncthreads();
    #pragma unroll
    for (int i=0;i<4;i++){
      int s = tid + i*256; int row = s>>3; int c0 = (s&7)*8;
      *(bf16x8*)&Ks[row][c0] = *(const bf16x8*)(k + (size_t)(t*128+row)*HID + head*64 + c0);
    }
    #pragma unroll
    for (int i=0;i<4;i++){
      int s = tid + i*256; int row = s>>3; int c0 = (s&7)*8;
      bf16x8 vv = *(const bf16x8*)(v + (size_t)(t*128+row)*HID + head*64 + c0);
      #pragma unroll
      for (int e=0;e<8;e++) Vt[c0+e][row] = vv[e];
    }
    __syncthreads();

    f32x4 sa[8];
    #pragma unroll
    for (int n=0;n<8;n++) sa[n] = zero4();
    #pragma unroll
    for (int ks=0;ks<2;ks++)
      #pragma unroll
      for (int n=0;n<8;n++){
        bf16x8 kf = *(const bf16x8*)&Ks[n*16 + (lane&15)][ks*32 + (lane>>4)*8];
        sa[n] = __builtin_amdgcn_mfma_f32_16x16x32_bf16(qf[ks], kf, sa[n], 0,0,0);
      }

    float pm[4], rs[4];
    #pragma unroll
    for (int r=0;r<4;r++){
      float mx = sa[0][r];
      #pragma unroll
      for (int n=1;n<8;n++) mx = fmaxf(mx, sa[n][r]);
      pm[r] = mx * 0.125f;
      #pragma unroll
      for (int off=1; off<16; off<<=1) pm[r] = fmaxf(pm[r], __shfl_xor(pm[r], off));
      float mnew  = fmaxf(mrow[r], pm[r]);
      float alpha = __expf(mrow[r] - mnew);
      mrow[r] = mnew; lrow[r] *= alpha;
      #pragma unroll
      for (int n=0;n<4;n++) o[n][r] *= alpha;
      rs[r] = 0.f;
    }
    #pragma unroll
    for (int n=0;n<8;n++)
      #pragma unroll
      for (int r=0;r<4;r++){
        float p = __expf(sa[n][r]*0.125f - mrow[r]);
        rs[r] += p;
        Ps[wave][(lane>>4)*4 + r][n*16 + (lane&15)] = (bf16_t)p;
      }
    #pragma unroll
    for (int r=0;r<4;r++){
      #pragma unroll
      for (int off=1; off<16; off<<=1) rs[r] += __shfl_xor(rs[r], off);
      lrow[r] += rs[r];
    }

    #pragma unroll
    for (int ksv=0;ksv<4;ksv++){
      bf16x8 pf = *(const bf16x8*)&Ps[wave][lane&15][ksv*32 + (lane>>4)*8];
      #pragma unroll
      for (int n=0;n<4;n++){
        bf16x8 vf = *(const bf16x8*)&Vt[n*16 + (lane&15)][ksv*32 + (lane>>4)*8];
        o[n] = __builtin_amdgcn_mfma_f32_16x16x32_bf16(pf, vf, o[n], 0,0,0);
      }
    }
  }

  #pragma unroll
  for (int n=0;n<4;n++)
    #pragma unroll
    for (int r=0;r<4;r++){
      const int gm = qrow0 + (lane>>4)*4 + r;
      const int gd = head*64 + n*16 + (lane&15);
      ctx[(size_t)gm*HID + swz_col(gm, gd)] = (bf16_t)(o[n][r] / lrow[r]);
    }
}

// ============ LN over 4096: x = sum(NP bf16 planes) + bias + resid(bf16 swz32) ============
template<int NP>
__global__ __launch_bounds__(256) void ln_final_kernel(
    const bf16_t* __restrict__ p, const bf16_t* __restrict__ resid,
    const float* __restrict__ bias,
    const float* __restrict__ g, const float* __restrict__ b,
    float* __restrict__ yf, bf16_t* __restrict__ yb)
{
  __shared__ float red[4];
  const int row = blockIdx.x, tid = threadIdx.x;
  const size_t base = (size_t)row * 4096;
  const size_t ps = (size_t)512*4096;
  const int c0 = tid*16;
  float vals[16];
  #pragma unroll
  for (int j=0;j<2;j++){
    bf16x8 rr = *(const bf16x8*)(resid + base + swz_col(row, c0 + j*8));
    const float4* bp4 = (const float4*)(bias + c0 + j*8);
    float4 b0 = bp4[0], b1 = bp4[1];
    vals[j*8+0] = (float)rr[0] + b0.x;  vals[j*8+1] = (float)rr[1] + b0.y;
    vals[j*8+2] = (float)rr[2] + b0.z;  vals[j*8+3] = (float)rr[3] + b0.w;
    vals[j*8+4] = (float)rr[4] + b1.x;  vals[j*8+5] = (float)rr[5] + b1.y;
    vals[j*8+6] = (float)rr[6] + b1.z;  vals[j*8+7] = (float)rr[7] + b1.w;
  }
  #pragma unroll
  for (int z=0;z<NP;z++)
    #pragma unroll
    for (int j=0;j<2;j++){
      bf16x8 w = *(const bf16x8*)(p + (size_t)z*ps + base + c0 + j*8);
      #pragma unroll
      for (int e=0;e<8;e++) vals[j*8+e] += (float)w[e];
    }
  float s = 0.f;
  #pragma unroll
  for (int i=0;i<16;i++) s += vals[i];
  #pragma unroll
  for (int off=1; off<64; off<<=1) s += __shfl_xor(s, off);
  if (!(tid&63)) red[tid>>6] = s;
  __syncthreads();
  const float mean = (red[0]+red[1]+red[2]+red[3]) * (1.0f/4096.0f);
  __syncthreads();
  float s2 = 0.f;
  #pragma unroll
  for (int i=0;i<16;i++){ float d = vals[i]-mean; s2 += d*d; }
  #pragma unroll
  for (int off=1; off<64; off<<=1) s2 += __shfl_xor(s2, off);
  if (!(tid&63)) red[tid>>6] = s2;
  __syncthreads();
  const float rstd = rsqrtf((red[0]+red[1]+red[2]+red[3])*(1.0f/4096.0f) + 1e-12f);
  #pragma unroll
  for (int j=0;j<2;j++){
    const float4* gp4 = (const float4*)(g + c0 + j*8);
    const float4* bp4 = (const float4*)(b + c0 + j*8);
    float4 g0 = gp4[0], g1 = gp4[1], bb0 = bp4[0], bb1 = bp4[1];
    float y[8];
    y[0] = (vals[j*8+0]-mean)*rstd*g0.x + bb0.x;
    y[1] = (vals[j*8+1]-mean)*rstd*g0.y + bb0.y;
    y[2] = (vals[j*8+2]-mean)*rstd*g0.z + bb0.z;
    y[3] = (vals[j*8+3]-mean)*rstd*g0.w + bb0.w;
    y[4] = (vals[j*8+4]-mean)*rstd*g1.x + bb1.x;
    y[5] = (vals[j*8+5]-mean)*rstd*g1.y + bb1.y;
    y[6] = (vals[j*8+6]-mean)*rstd*g1.z + bb1.z;
    y[7] = (vals[j*8+7]-mean)*rstd*g1.w + bb1.w;
    if (yf){
      float4* o4 = (float4*)(yf + base + c0 + j*8);
      float4 o0, o1;
      o0.x=y[0]; o0.y=y[1]; o0.z=y[2]; o0.w=y[3];
      o1.x=y[4]; o1.y=y[5]; o1.z=y[6]; o1.w=y[7];
      o4[0]=o0; o4[1]=o1;
    }
    if (yb){
      bf16x8 ov;
      #pragma unroll
      for (int e=0;e<8;e++) ov[e] = (bf16_t)y[e];
      *(bf16x8*)(yb + base + swz_col(row, c0 + j*8)) = ov;
    }
  }
}

// ============ embeddings + LN(128) -> bf16 swz32 ============
__global__ __launch_bounds__(128) void embed_ln_kernel(
    const float* __restrict__ we, const float* __restrict__ te, const float* __restrict__ pe,
    const float* __restrict__ g, const float* __restrict__ bb,
    const int* __restrict__ ids, const int* __restrict__ tt, const int* __restrict__ pos,
    bf16_t* __restrict__ out)
{
  __shared__ float red[2];
  const int row = blockIdx.x, tid = threadIdx.x;
  float e = we[(size_t)ids[row]*128 + tid] + te[(size_t)tt[row]*128 + tid] + pe[(size_t)pos[row]*128 + tid];
  float s = e;
  #pragma unroll
  for (int off=1; off<64; off<<=1) s += __shfl_xor(s, off);
  if (!(tid&63)) red[tid>>6] = s;
  __syncthreads();
  const float mean = (red[0]+red[1]) * (1.0f/128.0f);
  __syncthreads();
  float d = e - mean;
  float s2 = d*d;
  #pragma unroll
  for (int off=1; off<64; off<<=1) s2 += __shfl_xor(s2, off);
  if (!(tid&63)) red[tid>>6] = s2;
  __syncthreads();
  const float var = (red[0]+red[1]) * (1.0f/128.0f);
  float y = d * rsqrtf(var + 1e-12f) * g[tid] + bb[tid];
  out[(size_t)row*128 + swz_col(row, tid)] = (bf16_t)y;
}

// ============ launch ============
extern "C" void kernel_launch(void* const* d_in, const int* in_sizes, int n_in,
                              void* d_out, int out_size, void* d_ws, size_t ws_size,
                              hipStream_t stream) {
  const float* we   = (const float*)d_in[0];
  const float* te   = (const float*)d_in[1];
  const float* pe   = (const float*)d_in[2];
  const float* ln0g = (const float*)d_in[3];
  const float* ln0b = (const float*)d_in[4];
  const float* Wp   = (const float*)d_in[5];
  const float* bp   = (const float*)d_in[6];
  const float* Wq   = (const float*)d_in[7];
  const float* bq   = (const float*)d_in[8];
  const float* Wk   = (const float*)d_in[9];
  const float* bk   = (const float*)d_in[10];
  const float* Wv   = (const float*)d_in[11];
  const float* bv   = (const float*)d_in[12];
  const float* Wo   = (const float*)d_in[13];
  const float* bo   = (const float*)d_in[14];
  const float* ln1g = (const float*)d_in[15];
  const float* ln1b = (const float*)d_in[16];
  const float* Wf1  = (const float*)d_in[17];
  const float* bf1  = (const float*)d_in[18];
  const float* Wf2  = (const float*)d_in[19];
  const float* bf2  = (const float*)d_in[20];
  const float* ln2g = (const float*)d_in[21];
  const float* ln2b = (const float*)d_in[22];
  const int* ids = (const int*)d_in[23];
  const int* tt  = (const int*)d_in[24];
  const int* pos = (const int*)d_in[25];
  float* out = (float*)d_out;

  bf16_t* b16 = (bf16_t*)d_ws;
  const size_t M1 = (size_t)1024*1024;
  bf16_t* part_b = b16;                   // up to 16M elems (2 x 8M FFN1 planes max)
  bf16_t* hid_b  = b16 + 26*M1;           // 2M elems (swz32)
  bf16_t* h1_b   = b16 + 28*M1;           // 2M (swz32)
  bf16_t* ctxb   = b16 + 30*M1;           // 2M (swz32)
  bf16_t* qb     = b16 + 32*M1;           // 2M
  bf16_t* kb     = b16 + 34*M1;           // 2M
  bf16_t* vb     = b16 + 36*M1;           // 2M
  bf16_t* he_b   = b16 + 38*M1;           // 64K (swz32)
  bf16_t* gelu_b = b16 + 30*M1;           // 8M (reuses ctx/q/k/v, dead by FFN1 reduce)

  // embeddings + LN0 -> he_b (swz32)
  embed_ln_kernel<<<dim3(512),dim3(128),0,stream>>>(we,te,pe,ln0g,ln0b,ids,tt,pos,he_b);
  // hidden = h_e @ Wp^T + bp -> bf16 swz32 only   (128 blocks, nt=32, nz=1, ktn=4)
  gemm_kernel<4><<<dim3(128),dim3(256),0,stream>>>(he_b, Wp, bp, nullptr, hid_b, 4096, 128, 32, 1);
  // qkv bf16 partials, split-K=2  (768 blocks, ktn=64) -> part_b[2 x 6M]
  gemm_qkv_kernel<<<dim3(768),dim3(256),0,stream>>>(hid_b, Wq,Wk,Wv, bq,bk,bv, part_b);
  // sum 2 bf16 planes -> q,k,v bf16 linear  (3072 blocks exact)
  reduce_qkv_kernel<<<dim3(3072),dim3(256),0,stream>>>(part_b, qb, kb, vb);
  // attention -> ctx bf16 swz32   (512 blocks)
  attn_kernel<<<dim3(8,64),dim3(256),0,stream>>>(qb, kb, vb, ctxb);
  // attn_out bf16 partials = ctx @ Wo^T, split-K=8   (1024 blocks, nt=32, nz=8, ktn=16)
  gemm_kernel<2><<<dim3(1024),dim3(256),0,stream>>>(ctxb, Wo, nullptr, nullptr, part_b, 4096, 4096, 32, 8);
  // h1 = LN(sum 8 planes + bo + hidden_swz) -> bf16 swz32 only
  ln_final_kernel<8><<<dim3(512),dim3(256),0,stream>>>(part_b, hid_b, bo, ln1g, ln1b, nullptr, h1_b);
  // ffn1 bf16 partials = h1 @ Wf1^T + bf1, split-K=2   (1024 blocks, nt=128, nz=2, ktn=64)
  gemm_kernel<2><<<dim3(1024),dim3(256),0,stream>>>(h1_b, Wf1, bf1, nullptr, part_b, 16384, 4096, 128, 2);
  // gelu(sum 2 planes) -> gelu_b bf16 swz32  (4096 blocks exact)
  reduce_gelu_kernel<<<dim3(4096),dim3(256),0,stream>>>(part_b, gelu_b);
  // ff2 bf16 partials = gelu @ Wf2^T, split-K=8   (1024 blocks, nt=32, nz=8, ktn=64)
  gemm_kernel<2><<<dim3(1024),dim3(256),0,stream>>>(gelu_b, Wf2, nullptr, nullptr, part_b, 4096, 16384, 32, 8);
  // out = LN(sum 8 planes + bf2 + h1_swz) -> fp32
  ln_final_kernel<8><<<dim3(512),dim3(256),0,stream>>>(part_b, h1_b, bf2, ln2g, ln2b, out, nullptr);
}

// Round 25
// 447.118 us; speedup vs baseline: 1.4928x; 1.4928x over previous
//
#include <hip/hip_runtime.h>
#include <hip/hip_bf16.h>
#include <cmath>

typedef __bf16 bf16_t;
typedef bf16_t bf16x8 __attribute__((ext_vector_type(8)));
typedef float f32x4 __attribute__((ext_vector_type(4)));

__device__ __forceinline__ f32x4 zero4(){ f32x4 z; z[0]=0.f; z[1]=0.f; z[2]=0.f; z[3]=0.f; return z; }

__device__ __forceinline__ bf16x8 cvt8(float4 a, float4 b){
  bf16x8 r;
  r[0]=(bf16_t)a.x; r[1]=(bf16_t)a.y; r[2]=(bf16_t)a.z; r[3]=(bf16_t)a.w;
  r[4]=(bf16_t)b.x; r[5]=(bf16_t)b.y; r[6]=(bf16_t)b.z; r[7]=(bf16_t)b.w;
  return r;
}

__device__ __forceinline__ float gelu_tanh_f(float x){
  float x3 = x*x*x;
  return 0.5f*x*(1.0f + tanhf(0.7978845608028654f*(x + 0.044715f*x3)));
}

// chunk swizzle for bf16 A-operands: 16B chunk (col>>3)&3 XOR'd by (row>>1)&3
// maps aligned 8-elem chunks to aligned 8-elem chunks (bijective within 32 cols)
__device__ __forceinline__ int swz_col(int row, int col){
  return (col & ~31) | (((((col>>3)&3) ^ ((row>>1)&3)))<<3) | (col&7);
}

#if defined(__has_builtin)
#if __has_builtin(__builtin_amdgcn_global_load_lds)
#define HAS_GLDS 1
#endif
#endif

__device__ __forceinline__ void glds16(const void* g, void* l){
#ifdef HAS_GLDS
  __builtin_amdgcn_global_load_lds(
      (const __attribute__((address_space(1))) unsigned int*)g,
      (__attribute__((address_space(3))) unsigned int*)l, 16, 0, 0);
#else
  *(float4*)((char*)l + (threadIdx.x & 63)*16) = *(const float4*)g;
#endif
}

// ============ GEMM body: C[256,128] block, BK=32, 8 waves (4x2) ============
// Final schedule (r19/r23, 450us): raw s_barrier + lgkmcnt(0) only (no vmcnt(0)
// drain); A glds 3-ring issued 2 tiles ahead; B fp32 reg slot loaded 2 steps
// ahead, its ds_write reg-wait retires older VMEM in-order.  BM=256 halves
// W-duplication (convoy fix).  2 blocks/CU (VGPR-capped; r18/r24 proved 3
// infeasible for both BM shapes).
// EPI bits: 1 = fp32 store to Cf, 2 = bf16 linear to Cb, 4 = bf16 swz32 to Cb, 8 = gelu
template<int EPI>
__device__ __forceinline__ void gemm_body(
    const bf16_t* __restrict__ A, const float* __restrict__ Wt,
    const float* __restrict__ biast,
    float* __restrict__ Cf, bf16_t* __restrict__ Cb,
    int Nc, int K, int kt0, int ktn, int brow, int ccol0)
{
  __shared__ __align__(16) bf16_t As[3][256*32];   // 3 x 16 KB ring
  __shared__ __align__(16) bf16_t Bs[2][128*40];   // 2 x 10 KB (rows padded 80B)

  const int tid  = threadIdx.x;          // 0..511
  const int lane = tid & 63;
  const int wave = tid >> 6;             // 0..7
  const int wr = wave >> 1, wc = wave & 1;
  const int ca = ((lane>>4) ^ ((lane>>1)&3))*8;

  const bf16_t* srcA = A + (size_t)(brow + (tid>>2))*K + (tid&3)*8;
  const float*  srcB = Wt + (size_t)(tid>>2)*K + (tid&3)*8;

  auto issueA = [&](int buf, int kt){
    bf16_t* dA = &As[buf][wave*512];
    glds16(srcA + (size_t)kt*32,                  dA);
    glds16(srcA + (size_t)128*K + (size_t)kt*32,  dA + 4096);
  };
  auto loadB = [&](int kt, float4* g){
    const float4* p = (const float4*)(srcB + (size_t)kt*32);
    g[0]=p[0]; g[1]=p[1];
  };
  auto writeB = [&](int buf, const float4* g){
    bf16_t* d = &Bs[buf][(tid>>2)*40 + (tid&3)*8];
    *(bf16x8*)d = cvt8(g[0], g[1]);
  };

  f32x4 acc[4][4];
  #pragma unroll
  for (int m=0;m<4;m++)
    #pragma unroll
    for (int n=0;n<4;n++) acc[m][n] = zero4();

  auto ck = [&](int x){ return kt0 + (x < ktn ? x : ktn-1); };

  float4 sB[2];
  // ---- prologue: A(0),A(1) issued; B(0) staged; sB = B(1) left in flight
  issueA(0, ck(0));
  issueA(1, ck(1));
  {
    float4 g[2];
    loadB(ck(0), g);
    writeB(0, g);            // reg-wait on g retires A(0),A(1),B(0) (in-order)
  }
  loadB(ck(1), sB);
  asm volatile("s_waitcnt lgkmcnt(0)" ::: "memory");
  __builtin_amdgcn_s_barrier();

  for (int t=0; t<ktn; ++t){
    const int ra = t % 3, rb = t & 1;
    issueA((t+2)%3, ck(t+2));
    float4 gn[2];
    loadB(ck(t+2), gn);

    bf16x8 af[4], bfr[4];
    #pragma unroll
    for (int m=0;m<4;m++)
      af[m] = *(const bf16x8*)&As[ra][(wr*64 + m*16 + (lane&15))*32 + ca];
    #pragma unroll
    for (int n=0;n<4;n++)
      bfr[n] = *(const bf16x8*)&Bs[rb][(wc*64 + n*16 + (lane&15))*40 + (lane>>4)*8];
    #pragma unroll
    for (int m=0;m<4;m++)
      #pragma unroll
      for (int n=0;n<4;n++)
        acc[m][n] = __builtin_amdgcn_mfma_f32_16x16x32_bf16(af[m], bfr[n], acc[m][n], 0,0,0);

    writeB((t+1)&1, sB);     // sB = B(t+1), issued last step; wait retires A(t+1) too
    sB[0]=gn[0]; sB[1]=gn[1];
    asm volatile("s_waitcnt lgkmcnt(0)" ::: "memory");
    __builtin_amdgcn_s_barrier();
  }

  #pragma unroll
  for (int m=0;m<4;m++){
    #pragma unroll
    for (int n=0;n<4;n++){
      const int col = wc*64 + n*16 + (lane&15);
      const float bv = biast ? biast[col] : 0.f;
      #pragma unroll
      for (int r=0;r<4;r++){
        const int gm = brow + wr*64 + m*16 + (lane>>4)*4 + r;
        float v = acc[m][n][r] + bv;
        if (EPI & 8) v = gelu_tanh_f(v);
        if (EPI & 1) Cf[(size_t)gm*Nc + ccol0 + col] = v;
        if (EPI & 2) Cb[(size_t)gm*Nc + ccol0 + col] = (bf16_t)v;
        if (EPI & 4) Cb[(size_t)gm*Nc + swz_col(gm, ccol0 + col)] = (bf16_t)v;
      }
    }
  }
}

// XCD-grouped decode: lin = r + 8*(m + 2*q); o = r + 8q. The 2 m-blocks sharing a
// W-tile are congruent mod 8 -> same XCD L2. o-count must be % 8 == 0.
// Cb/Cf are pre-offset by the split-K plane (z*512*N) for partial outputs.
template<int EPI>
__global__ __launch_bounds__(512,4) void gemm_kernel(
    const bf16_t* __restrict__ A, const float* __restrict__ W,
    const float* __restrict__ bias,
    float* __restrict__ Cf, bf16_t* __restrict__ Cb, int N, int K, int nt, int nz)
{
  const int lin = blockIdx.x;
  const int r = lin & 7;
  const int t = lin >> 3;
  const int m = t & 1;
  const int o = r + 8*(t>>1);
  const int n_tile = o % nt;
  const int z = o / nt;
  const int ktn = (K>>5) / nz;
  const float* b = (z==0 && bias) ? bias + n_tile*128 : nullptr;
  gemm_body<EPI>(A, W + (size_t)(n_tile*128)*K, b,
                 (EPI&1) ? Cf + (size_t)z*512*N : nullptr,
                 (EPI&6) ? Cb + (size_t)z*512*N : nullptr,
                 N, K, z*ktn, ktn, m*256, n_tile*128);
}

// fused QKV, split-K=2: o in [0,192): n_tile = o%96 (12288-wide plane), z = o/96
// K=4096 -> 128 K-tiles; each z covers 64 (z*64, ktn=64).  Grid 384 = one
// co-resident round at 2 blocks/CU; bf16 partials (2 planes).
__global__ __launch_bounds__(512,4) void gemm_qkv_kernel(
    const bf16_t* __restrict__ A,
    const float* __restrict__ W0, const float* __restrict__ W1, const float* __restrict__ W2,
    const float* __restrict__ b0, const float* __restrict__ b1, const float* __restrict__ b2,
    bf16_t* __restrict__ Cb)
{
  const int lin = blockIdx.x;
  const int r = lin & 7;
  const int t = lin >> 3;
  const int m = t & 1;
  const int o = r + 8*(t>>1);      // [0,192)
  const int n_tile = o % 96;
  const int z = o / 96;            // 0..1
  const int which = n_tile >> 5;
  const int lc = (n_tile & 31) * 128;
  const float* W    = (which==0) ? W0 : ((which==1) ? W1 : W2);
  const float* bia  = (which==0) ? b0 : ((which==1) ? b1 : b2);
  const float* b = (z==0) ? bia + lc : nullptr;
  gemm_body<2>(A, W + (size_t)lc*4096, b, nullptr,
               Cb + (size_t)z*512*12288,
               12288, 4096, z*64, 64, m*256, n_tile*128);
}

// ============ reduce: qkv partials (2 bf16 planes of [512,12288]) -> q,k,v bf16 linear ============
__global__ __launch_bounds__(256) void reduce_qkv_kernel(
    const bf16_t* __restrict__ p, bf16_t* __restrict__ q,
    bf16_t* __restrict__ k, bf16_t* __restrict__ v)
{
  const size_t plane = (size_t)512*12288;
  const int i = (blockIdx.x*256 + threadIdx.x)*8;   // grid 3072 covers exactly
  bf16x8 w0 = *(const bf16x8*)(p + i);
  bf16x8 w1 = *(const bf16x8*)(p + plane + i);
  bf16x8 val;
  #pragma unroll
  for (int e=0;e<8;e++) val[e] = (bf16_t)((float)w0[e] + (float)w1[e]);
  const int row = i / 12288;
  const int col = i - row*12288;
  bf16_t* dst = (col<4096) ? q : ((col<8192) ? k : v);
  *(bf16x8*)(dst + (size_t)row*4096 + (col & 4095)) = val;
}

// ============ reduce: ffn1 partials (2 bf16 planes of [512,16384]) + gelu -> bf16 swz32 ============
__global__ __launch_bounds__(256) void reduce_gelu_kernel(
    const bf16_t* __restrict__ p, bf16_t* __restrict__ out)
{
  const size_t plane = (size_t)512*16384;
  const int i = (blockIdx.x*256 + threadIdx.x)*8;   // grid 4096 covers exactly
  bf16x8 w0 = *(const bf16x8*)(p + i);
  bf16x8 w1 = *(const bf16x8*)(p + plane + i);
  bf16x8 val;
  #pragma unroll
  for (int e=0;e<8;e++) val[e] = (bf16_t)gelu_tanh_f((float)w0[e] + (float)w1[e]);
  const int row = i >> 14;
  const int col = i & 16383;
  *(bf16x8*)(out + (size_t)row*16384 + (size_t)swz_col(row, col)) = val;
}

// ============ flash attention: grid (8 qblocks, 64 heads), 256 thr, 16 q-rows/wave ============
__global__ void attn_kernel(
    const bf16_t* __restrict__ q, const bf16_t* __restrict__ k,
    const bf16_t* __restrict__ v, bf16_t* __restrict__ ctx)
{
  constexpr int HID = 4096;
  const int qblk = blockIdx.x, head = blockIdx.y;
  const int tid = threadIdx.x, lane = tid & 63, wave = tid >> 6;

  __shared__ __align__(16) bf16_t Ks[128][72];
  __shared__ __align__(16) bf16_t Vt[64][136];
  __shared__ __align__(16) bf16_t Ps[4][16][136];

  bf16x8 qf[2];
  const int qrow0 = qblk*64 + wave*16;
  #pragma unroll
  for (int ks=0;ks<2;ks++)
    qf[ks] = *(const bf16x8*)(q + (size_t)(qrow0 + (lane&15))*HID + head*64 + ks*32 + (lane>>4)*8);

  f32x4 o[4];
  float mrow[4], lrow[4];
  #pragma unroll
  for (int n=0;n<4;n++) o[n] = zero4();
  #pragma unroll
  for (int r=0;r<4;r++){ mrow[r] = -1e30f; lrow[r] = 0.f; }

  for (int t=0; t<4; ++t){
    __syncthreads();
    #pragma unroll
    for (int i=0;i<4;i++){
      int s = tid + i*256; int row = s>>3; int c0 = (s&7)*8;
      *(bf16x8*)&Ks[row][c0] = *(const bf16x8*)(k + (size_t)(t*128+row)*HID + head*64 + c0);
    }
    #pragma unroll
    for (int i=0;i<4;i++){
      int s = tid + i*256; int row = s>>3; int c0 = (s&7)*8;
      bf16x8 vv = *(const bf16x8*)(v + (size_t)(t*128+row)*HID + head*64 + c0);
      #pragma unroll
      for (int e=0;e<8;e++) Vt[c0+e][row] = vv[e];
    }
    __syncthreads();

    f32x4 sa[8];
    #pragma unroll
    for (int n=0;n<8;n++) sa[n] = zero4();
    #pragma unroll
    for (int ks=0;ks<2;ks++)
      #pragma unroll
      for (int n=0;n<8;n++){
        bf16x8 kf = *(const bf16x8*)&Ks[n*16 + (lane&15)][ks*32 + (lane>>4)*8];
        sa[n] = __builtin_amdgcn_mfma_f32_16x16x32_bf16(qf[ks], kf, sa[n], 0,0,0);
      }

    float pm[4], rs[4];
    #pragma unroll
    for (int r=0;r<4;r++){
      float mx = sa[0][r];
      #pragma unroll
      for (int n=1;n<8;n++) mx = fmaxf(mx, sa[n][r]);
      pm[r] = mx * 0.125f;
      #pragma unroll
      for (int off=1; off<16; off<<=1) pm[r] = fmaxf(pm[r], __shfl_xor(pm[r], off));
      float mnew  = fmaxf(mrow[r], pm[r]);
      float alpha = __expf(mrow[r] - mnew);
      mrow[r] = mnew; lrow[r] *= alpha;
      #pragma unroll
      for (int n=0;n<4;n++) o[n][r] *= alpha;
      rs[r] = 0.f;
    }
    #pragma unroll
    for (int n=0;n<8;n++)
      #pragma unroll
      for (int r=0;r<4;r++){
        float p = __expf(sa[n][r]*0.125f - mrow[r]);
        rs[r] += p;
        Ps[wave][(lane>>4)*4 + r][n*16 + (lane&15)] = (bf16_t)p;
      }
    #pragma unroll
    for (int r=0;r<4;r++){
      #pragma unroll
      for (int off=1; off<16; off<<=1) rs[r] += __shfl_xor(rs[r], off);
      lrow[r] += rs[r];
    }

    #pragma unroll
    for (int ksv=0;ksv<4;ksv++){
      bf16x8 pf = *(const bf16x8*)&Ps[wave][lane&15][ksv*32 + (lane>>4)*8];
      #pragma unroll
      for (int n=0;n<4;n++){
        bf16x8 vf = *(const bf16x8*)&Vt[n*16 + (lane&15)][ksv*32 + (lane>>4)*8];
        o[n] = __builtin_amdgcn_mfma_f32_16x16x32_bf16(pf, vf, o[n], 0,0,0);
      }
    }
  }

  #pragma unroll
  for (int n=0;n<4;n++)
    #pragma unroll
    for (int r=0;r<4;r++){
      const int gm = qrow0 + (lane>>4)*4 + r;
      const int gd = head*64 + n*16 + (lane&15);
      ctx[(size_t)gm*HID + swz_col(gm, gd)] = (bf16_t)(o[n][r] / lrow[r]);
    }
}

// ============ LN over 4096: x = sum(NP bf16 planes) + bias + resid(bf16 swz32) ============
// vectorized: each of 256 threads owns 16 consecutive cols (2x bf16x8 per stream)
template<int NP>
__global__ __launch_bounds__(256) void ln_final_kernel(
    const bf16_t* __restrict__ p, const bf16_t* __restrict__ resid,
    const float* __restrict__ bias,
    const float* __restrict__ g, const float* __restrict__ b,
    float* __restrict__ yf, bf16_t* __restrict__ yb)
{
  __shared__ float red[4];
  const int row = blockIdx.x, tid = threadIdx.x;
  const size_t base = (size_t)row * 4096;
  const size_t ps = (size_t)512*4096;
  const int c0 = tid*16;
  float vals[16];
  // residual (swz32 bf16) + bias (fp32)
  #pragma unroll
  for (int j=0;j<2;j++){
    bf16x8 rr = *(const bf16x8*)(resid + base + swz_col(row, c0 + j*8));
    const float4* bp4 = (const float4*)(bias + c0 + j*8);
    float4 b0 = bp4[0], b1 = bp4[1];
    vals[j*8+0] = (float)rr[0] + b0.x;  vals[j*8+1] = (float)rr[1] + b0.y;
    vals[j*8+2] = (float)rr[2] + b0.z;  vals[j*8+3] = (float)rr[3] + b0.w;
    vals[j*8+4] = (float)rr[4] + b1.x;  vals[j*8+5] = (float)rr[5] + b1.y;
    vals[j*8+6] = (float)rr[6] + b1.z;  vals[j*8+7] = (float)rr[7] + b1.w;
  }
  // partial planes (linear bf16)
  #pragma unroll
  for (int z=0;z<NP;z++)
    #pragma unroll
    for (int j=0;j<2;j++){
      bf16x8 w = *(const bf16x8*)(p + (size_t)z*ps + base + c0 + j*8);
      #pragma unroll
      for (int e=0;e<8;e++) vals[j*8+e] += (float)w[e];
    }
  float s = 0.f;
  #pragma unroll
  for (int i=0;i<16;i++) s += vals[i];
  #pragma unroll
  for (int off=1; off<64; off<<=1) s += __shfl_xor(s, off);
  if (!(tid&63)) red[tid>>6] = s;
  __syncthreads();
  const float mean = (red[0]+red[1]+red[2]+red[3]) * (1.0f/4096.0f);
  __syncthreads();
  float s2 = 0.f;
  #pragma unroll
  for (int i=0;i<16;i++){ float d = vals[i]-mean; s2 += d*d; }
  #pragma unroll
  for (int off=1; off<64; off<<=1) s2 += __shfl_xor(s2, off);
  if (!(tid&63)) red[tid>>6] = s2;
  __syncthreads();
  const float rstd = rsqrtf((red[0]+red[1]+red[2]+red[3])*(1.0f/4096.0f) + 1e-12f);
  #pragma unroll
  for (int j=0;j<2;j++){
    const float4* gp4 = (const float4*)(g + c0 + j*8);
    const float4* bp4 = (const float4*)(b + c0 + j*8);
    float4 g0 = gp4[0], g1 = gp4[1], bb0 = bp4[0], bb1 = bp4[1];
    float y[8];
    y[0] = (vals[j*8+0]-mean)*rstd*g0.x + bb0.x;
    y[1] = (vals[j*8+1]-mean)*rstd*g0.y + bb0.y;
    y[2] = (vals[j*8+2]-mean)*rstd*g0.z + bb0.z;
    y[3] = (vals[j*8+3]-mean)*rstd*g0.w + bb0.w;
    y[4] = (vals[j*8+4]-mean)*rstd*g1.x + bb1.x;
    y[5] = (vals[j*8+5]-mean)*rstd*g1.y + bb1.y;
    y[6] = (vals[j*8+6]-mean)*rstd*g1.z + bb1.z;
    y[7] = (vals[j*8+7]-mean)*rstd*g1.w + bb1.w;
    if (yf){
      float4* o4 = (float4*)(yf + base + c0 + j*8);
      float4 o0, o1;
      o0.x=y[0]; o0.y=y[1]; o0.z=y[2]; o0.w=y[3];
      o1.x=y[4]; o1.y=y[5]; o1.z=y[6]; o1.w=y[7];
      o4[0]=o0; o4[1]=o1;
    }
    if (yb){
      bf16x8 ov;
      #pragma unroll
      for (int e=0;e<8;e++) ov[e] = (bf16_t)y[e];
      *(bf16x8*)(yb + base + swz_col(row, c0 + j*8)) = ov;
    }
  }
}

// ============ embeddings + LN(128) -> bf16 swz32 ============
__global__ __launch_bounds__(128) void embed_ln_kernel(
    const float* __restrict__ we, const float* __restrict__ te, const float* __restrict__ pe,
    const float* __restrict__ g, const float* __restrict__ bb,
    const int* __restrict__ ids, const int* __restrict__ tt, const int* __restrict__ pos,
    bf16_t* __restrict__ out)
{
  __shared__ float red[2];
  const int row = blockIdx.x, tid = threadIdx.x;
  float e = we[(size_t)ids[row]*128 + tid] + te[(size_t)tt[row]*128 + tid] + pe[(size_t)pos[row]*128 + tid];
  float s = e;
  #pragma unroll
  for (int off=1; off<64; off<<=1) s += __shfl_xor(s, off);
  if (!(tid&63)) red[tid>>6] = s;
  __syncthreads();
  const float mean = (red[0]+red[1]) * (1.0f/128.0f);
  __syncthreads();
  float d = e - mean;
  float s2 = d*d;
  #pragma unroll
  for (int off=1; off<64; off<<=1) s2 += __shfl_xor(s2, off);
  if (!(tid&63)) red[tid>>6] = s2;
  __syncthreads();
  const float var = (red[0]+red[1]) * (1.0f/128.0f);
  float y = d * rsqrtf(var + 1e-12f) * g[tid] + bb[tid];
  out[(size_t)row*128 + swz_col(row, tid)] = (bf16_t)y;
}

// ============ launch ============
extern "C" void kernel_launch(void* const* d_in, const int* in_sizes, int n_in,
                              void* d_out, int out_size, void* d_ws, size_t ws_size,
                              hipStream_t stream) {
  const float* we   = (const float*)d_in[0];
  const float* te   = (const float*)d_in[1];
  const float* pe   = (const float*)d_in[2];
  const float* ln0g = (const float*)d_in[3];
  const float* ln0b = (const float*)d_in[4];
  const float* Wp   = (const float*)d_in[5];
  const float* bp   = (const float*)d_in[6];
  const float* Wq   = (const float*)d_in[7];
  const float* bq   = (const float*)d_in[8];
  const float* Wk   = (const float*)d_in[9];
  const float* bk   = (const float*)d_in[10];
  const float* Wv   = (const float*)d_in[11];
  const float* bv   = (const float*)d_in[12];
  const float* Wo   = (const float*)d_in[13];
  const float* bo   = (const float*)d_in[14];
  const float* ln1g = (const float*)d_in[15];
  const float* ln1b = (const float*)d_in[16];
  const float* Wf1  = (const float*)d_in[17];
  const float* bf1  = (const float*)d_in[18];
  const float* Wf2  = (const float*)d_in[19];
  const float* bf2  = (const float*)d_in[20];
  const float* ln2g = (const float*)d_in[21];
  const float* ln2b = (const float*)d_in[22];
  const int* ids = (const int*)d_in[23];
  const int* tt  = (const int*)d_in[24];
  const int* pos = (const int*)d_in[25];
  float* out = (float*)d_out;

  bf16_t* b16 = (bf16_t*)d_ws;
  const size_t M1 = (size_t)1024*1024;
  bf16_t* part_b = b16;                   // up to 16M elems (2 x 8M FFN1 planes max)
  bf16_t* hid_b  = b16 + 26*M1;           // 2M elems (swz32)
  bf16_t* h1_b   = b16 + 28*M1;           // 2M (swz32)
  bf16_t* ctxb   = b16 + 30*M1;           // 2M (swz32)
  bf16_t* qb     = b16 + 32*M1;           // 2M
  bf16_t* kb     = b16 + 34*M1;           // 2M
  bf16_t* vb     = b16 + 36*M1;           // 2M
  bf16_t* he_b   = b16 + 38*M1;           // 64K (swz32)
  bf16_t* gelu_b = b16 + 30*M1;           // 8M (reuses ctx/q/k/v, dead by FFN1 reduce)

  // embeddings + LN0 -> he_b (swz32)
  embed_ln_kernel<<<dim3(512),dim3(128),0,stream>>>(we,te,pe,ln0g,ln0b,ids,tt,pos,he_b);
  // hidden = h_e @ Wp^T + bp -> bf16 swz32 only   (64 blocks, nt=32, nz=1, ktn=4)
  gemm_kernel<4><<<dim3(64),dim3(512),0,stream>>>(he_b, Wp, bp, nullptr, hid_b, 4096, 128, 32, 1);
  // qkv bf16 partials, split-K=2  (384 blocks, ktn=64) -> part_b[2 x 6M]
  gemm_qkv_kernel<<<dim3(384),dim3(512),0,stream>>>(hid_b, Wq,Wk,Wv, bq,bk,bv, part_b);
  // sum 2 bf16 planes -> q,k,v bf16 linear  (3072 blocks exact)
  reduce_qkv_kernel<<<dim3(3072),dim3(256),0,stream>>>(part_b, qb, kb, vb);
  // attention -> ctx bf16 swz32   (512 blocks)
  attn_kernel<<<dim3(8,64),dim3(256),0,stream>>>(qb, kb, vb, ctxb);
  // attn_out bf16 partials = ctx @ Wo^T, split-K=8   (512 blocks, nt=32, nz=8, ktn=16)
  gemm_kernel<2><<<dim3(512),dim3(512),0,stream>>>(ctxb, Wo, nullptr, nullptr, part_b, 4096, 4096, 32, 8);
  // h1 = LN(sum 8 planes + bo + hidden_swz) -> bf16 swz32 only
  ln_final_kernel<8><<<dim3(512),dim3(256),0,stream>>>(part_b, hid_b, bo, ln1g, ln1b, nullptr, h1_b);
  // ffn1 bf16 partials = h1 @ Wf1^T + bf1, split-K=2   (512 blocks, nt=128, nz=2, ktn=64)
  gemm_kernel<2><<<dim3(512),dim3(512),0,stream>>>(h1_b, Wf1, bf1, nullptr, part_b, 16384, 4096, 128, 2);
  // gelu(sum 2 planes) -> gelu_b bf16 swz32  (4096 blocks exact)
  reduce_gelu_kernel<<<dim3(4096),dim3(256),0,stream>>>(part_b, gelu_b);
  // ff2 bf16 partials = gelu @ Wf2^T, split-K=8   (512 blocks, nt=32, nz=8, ktn=64)
  gemm_kernel<2><<<dim3(512),dim3(512),0,stream>>>(gelu_b, Wf2, nullptr, nullptr, part_b, 4096, 16384, 32, 8);
  // out = LN(sum 8 planes + bf2 + h1_swz) -> fp32
  ln_final_kernel<8><<<dim3(512),dim3(256),0,stream>>>(part_b, h1_b, bf2, ln2g, ln2b, out, nullptr);
}